// Round 4
// baseline (105.271 us; speedup 1.0000x reference)
//
#include <hip/hip_runtime.h>
#include <hip/hip_bf16.h>
#include <math.h>

// Problem constants
#define N_TOK 16384
#define I_DIM 128
#define O_DIM 128
#define G_DIM 16
// GEMM tiling
#define BN 64                       // n-rows per block
#define CI 4                        // i-values per K-chunk
#define KC (CI * G_DIM * 2)         // 128 k per chunk
#define NCHUNK (I_DIM / CI)         // 32 chunks
#define A_STRIDE 136                // bf16 elems per LDS A row (272 B = 17 granules, odd)
#define ABUF (BN * A_STRIDE)        // 8704 elems = 17408 B per A buffer
#define C_STRIDE 132                // floats per LDS C row (epilogue)

typedef __bf16 bf16x8 __attribute__((ext_vector_type(8)));
typedef float  f32x4  __attribute__((ext_vector_type(4)));

// ---------------------------------------------------------------------------
// Pack cos/sin amplitudes (O,I,G) fp32 -> bf16 Bp in MFMA-FRAGMENT order:
//   frag(c, cg, ks, ot) = ((c*4 + cg)*4 + ks)*2 + ot, 64 lanes x 8 bf16 each.
//   lane (quad*16 + row16) holds B[o = cg*32+ot*16+row16][k = ks*32+quad*8+j],
//   k decode: i = c*4+ks (one i per k-step), g = quad*4 + (j>>1), s = j&1.
// Thread mapping chosen for COALESCED READS (gq fastest -> contiguous float4).
// ---------------------------------------------------------------------------
__global__ __launch_bounds__(256) void fkan_pack_b(
    const float* __restrict__ cosA, const float* __restrict__ sinA,
    __bf16* __restrict__ Bp)
{
    int tid = blockIdx.x * 256 + threadIdx.x;   // 0 .. 65535
    int gq  = tid & 3;                          // g-quad (0..3) -> quad
    int i   = (tid >> 2) & 127;
    int o   = tid >> 9;
    int c   = i >> 2, ks = i & 3;
    int cg  = o >> 5, ot = (o >> 4) & 1, row16 = o & 15;
    int lane = gq * 16 + row16;
    size_t sbase = ((size_t)o * I_DIM + i) * G_DIM + gq * 4;
    float4 cv = *(const float4*)(cosA + sbase);
    float4 sv = *(const float4*)(sinA + sbase);
    bf16x8 v;
    v[0] = (__bf16)cv.x; v[1] = (__bf16)sv.x;
    v[2] = (__bf16)cv.y; v[3] = (__bf16)sv.y;
    v[4] = (__bf16)cv.z; v[5] = (__bf16)sv.z;
    v[6] = (__bf16)cv.w; v[7] = (__bf16)sv.w;
    size_t frag = (((size_t)c * 4 + cg) * 4 + ks) * 2 + ot;
    *(bf16x8*)(Bp + (frag * 64 + lane) * 8) = v;
}

// ---------------------------------------------------------------------------
// Fused: features (cos/sin of x*freq) -> bf16 MFMA GEMM -> bias -> LayerNorm
// Grid: 256 blocks x 512 threads (8 waves, 2/SIMD). Block tile 64n x 128o.
// Wave tile: 32n x 32o (rg = wave>>2, cg = wave&3; 2x2 of 16x16x32 MFMA).
// B: fragment-packed global loads (1 contiguous KB per instr), register
// double-buffered one chunk ahead; rg-pair waves duplicate B reads (L1/L2).
// A: features double-buffered in LDS, split-harmonic staging (shalf),
// ONE raw barrier per chunk, lgkm-only drain (B loads span barriers).
// ---------------------------------------------------------------------------
__global__ __launch_bounds__(512) void fkan_main(
    const float* __restrict__ x,
    const __bf16* __restrict__ Bp,
    const float* __restrict__ bias,
    const float* __restrict__ gamma,
    const float* __restrict__ beta,
    float* __restrict__ out)
{
    // LDS: 2 x A buffer (64 x 136 bf16 = 17408 B each) = 34816 B.
    // Epilogue C tile (64 x 132 f32 = 33792 B) reuses the same memory.
    __shared__ __align__(16) __bf16 smem[2 * ABUF];
    __bf16* A0 = smem;
    __bf16* A1 = smem + ABUF;

    const int t     = threadIdx.x;
    const int lane  = t & 63;
    const int wave  = t >> 6;          // 0..7
    const int rg    = wave >> 2;       // row-group: rows rg*32 .. rg*32+31
    const int cg    = wave & 3;        // col-group: cols cg*32 .. cg*32+31
    const int row16 = lane & 15;
    const int quad  = lane >> 4;
    const int n0    = blockIdx.x * BN;

    // feature-staging role: (row, i-within-chunk, g-half). shalf wave-uniform.
    const int srow  = (t & 255) >> 2;  // 0..63
    const int sil   = t & 3;           // 0..3
    const int shalf = t >> 8;          // 0: g=1..8, 1: g=9..16

    f32x4 acc[2][2];
#pragma unroll
    for (int mt = 0; mt < 2; ++mt)
#pragma unroll
        for (int ot = 0; ot < 2; ++ot)
            acc[mt][ot] = (f32x4){0.f, 0.f, 0.f, 0.f};

    bf16x8 bA[2][4], bB[2][4];         // [ot][ks] register double-buffer for B

    auto ld_x = [&](int c) -> float {
        return x[(size_t)(n0 + srow) * I_DIM + c * CI + sil];
    };

    // ---- fragment-packed coalesced B load: 8 x dwordx4 per wave per chunk ----
    auto ld_b = [&](int c, bf16x8 (&b)[2][4]) {
        const bf16x8* base = (const bf16x8*)Bp + ((size_t)(c * 4 + cg) * 8) * 64 + lane;
#pragma unroll
        for (int ks = 0; ks < 4; ++ks)
#pragma unroll
            for (int ot = 0; ot < 2; ++ot)
                b[ot][ks] = base[(ks * 2 + ot) * 64];
    };

    // ---- compute 16 bf16 features (one g-half) for (srow, c*4+sil) -> LDS ----
    auto stage_a = [&](float xv, __bf16* Ab) {
        float s1, c1;
        __sincosf(xv, &s1, &c1);
        float cb = c1, sb = s1;        // base = (cos x, sin x)  [g=1]
        if (shalf) {                   // base = (cos 9x, sin 9x): 3 doublings + 1 step
            float cd = c1, sd = s1;
#pragma unroll
            for (int d = 0; d < 3; ++d) {
                float cn = cd * cd - sd * sd;
                float sn = 2.f * cd * sd;
                cd = cn; sd = sn;
            }
            cb = cd * c1 - sd * s1;
            sb = sd * c1 + cd * s1;
        }
        __align__(16) __bf16 feat[16];
        float cc_ = cb, ss_ = sb;
#pragma unroll
        for (int j = 0; j < 8; ++j) {  // 8 harmonics from base, step by x
            feat[2 * j]     = (__bf16)cc_;
            feat[2 * j + 1] = (__bf16)ss_;
            float cn = cc_ * c1 - ss_ * s1;
            float sn = ss_ * c1 + cc_ * s1;
            cc_ = cn; ss_ = sn;
        }
        bf16x8* dst = (bf16x8*)(Ab + srow * A_STRIDE + sil * 32 + shalf * 16);
        dst[0] = ((const bf16x8*)feat)[0];
        dst[1] = ((const bf16x8*)feat)[1];
    };

    // ---- one K-chunk phase: prefetch c+1 (B regs, A LDS, x scalar), MFMA c ----
    auto phase = [&](int c, const __bf16* Ar, __bf16* Aw,
                     bf16x8 (&bcur)[2][4], bf16x8 (&bnext)[2][4], float xs, float& xn) {
        const bool pf = (c + 1 < NCHUNK);
        if (pf) ld_b(c + 1, bnext);          // coalesced global loads, in flight
        if (c + 2 < NCHUNK) xn = ld_x(c + 2);
        if (pf) stage_a(xs, Aw);             // VALU chain + 2 ds_write (other buffer)

        __builtin_amdgcn_s_setprio(1);
#pragma unroll
        for (int ks = 0; ks < 4; ++ks) {
            bf16x8 a0 = *(const bf16x8*)(Ar + (rg * 32 + row16) * A_STRIDE + ks * 32 + quad * 8);
            bf16x8 a1 = *(const bf16x8*)(Ar + (rg * 32 + 16 + row16) * A_STRIDE + ks * 32 + quad * 8);
            acc[0][0] = __builtin_amdgcn_mfma_f32_16x16x32_bf16(a0, bcur[0][ks], acc[0][0], 0, 0, 0);
            acc[0][1] = __builtin_amdgcn_mfma_f32_16x16x32_bf16(a0, bcur[1][ks], acc[0][1], 0, 0, 0);
            acc[1][0] = __builtin_amdgcn_mfma_f32_16x16x32_bf16(a1, bcur[0][ks], acc[1][0], 0, 0, 0);
            acc[1][1] = __builtin_amdgcn_mfma_f32_16x16x32_bf16(a1, bcur[1][ks], acc[1][1], 0, 0, 0);
        }
        __builtin_amdgcn_s_setprio(0);

        asm volatile("s_waitcnt lgkmcnt(0)" ::: "memory");  // A writes visible, reads retired
        __builtin_amdgcn_sched_barrier(0);
        __builtin_amdgcn_s_barrier();        // vmcnt NOT drained: B prefetch spans barrier
    };

    // ---- prologue: stage chunk 0 (the only exposed latency) ----
    float xA = ld_x(0);
    float xB;
    ld_b(0, bA);
    stage_a(xA, A0);
    xB = ld_x(1);
    asm volatile("s_waitcnt lgkmcnt(0)" ::: "memory");
    __builtin_amdgcn_s_barrier();

    for (int cc = 0; cc < NCHUNK / 2; ++cc) {
        phase(2 * cc,     A0, A1, bA, bB, xB, xA);   // stages chunk 2cc+1 (x = xB)
        phase(2 * cc + 1, A1, A0, bB, bA, xA, xB);   // stages chunk 2cc+2 (x = xA)
    }

    // ---- epilogue: acc -> LDS C, bias + LayerNorm over O=128, store fp32 ----
    // C/D layout: col(o within 16) = lane&15, row(m within 16) = quad*4 + reg
    float* Cs = (float*)smem;          // safe: last barrier retired all A-buffer ops
#pragma unroll
    for (int mt = 0; mt < 2; ++mt)
#pragma unroll
        for (int ot = 0; ot < 2; ++ot)
#pragma unroll
            for (int r = 0; r < 4; ++r)
                Cs[(rg * 32 + mt * 16 + quad * 4 + r) * C_STRIDE
                   + cg * 32 + ot * 16 + row16] = acc[mt][ot][r];
    __syncthreads();

    {
        const int r  = t >> 3;         // row within block (0..63)
        const int oc = t & 7;          // eighth of the O dim (16 cols each)
        const float* crow = Cs + r * C_STRIDE + oc * 16;
        float vals[16];
        float sum = 0.f, sumsq = 0.f;
#pragma unroll
        for (int j4 = 0; j4 < 4; ++j4) {
            f32x4 v4 = *(const f32x4*)(crow + 4 * j4);
#pragma unroll
            for (int e = 0; e < 4; ++e) {
                float v = v4[e] + bias[oc * 16 + 4 * j4 + e];
                vals[4 * j4 + e] = v;
                sum += v;
                sumsq += v * v;
            }
        }
        // combine the 8 threads of this row (adjacent lanes, bits 0-2)
        sum   += __shfl_xor(sum, 1);   sum   += __shfl_xor(sum, 2);   sum   += __shfl_xor(sum, 4);
        sumsq += __shfl_xor(sumsq, 1); sumsq += __shfl_xor(sumsq, 2); sumsq += __shfl_xor(sumsq, 4);
        float mu   = sum * (1.0f / O_DIM);
        float var  = sumsq * (1.0f / O_DIM) - mu * mu;
        float rstd = rsqrtf(var + 1e-5f);

        float* orow = out + (size_t)(n0 + r) * O_DIM + oc * 16;
#pragma unroll
        for (int j4 = 0; j4 < 4; ++j4) {
            float4 o4;
            o4.x = (vals[4*j4+0] - mu) * rstd * gamma[oc*16 + 4*j4+0] + beta[oc*16 + 4*j4+0];
            o4.y = (vals[4*j4+1] - mu) * rstd * gamma[oc*16 + 4*j4+1] + beta[oc*16 + 4*j4+1];
            o4.z = (vals[4*j4+2] - mu) * rstd * gamma[oc*16 + 4*j4+2] + beta[oc*16 + 4*j4+2];
            o4.w = (vals[4*j4+3] - mu) * rstd * gamma[oc*16 + 4*j4+3] + beta[oc*16 + 4*j4+3];
            *(float4*)(orow + 4 * j4) = o4;
        }
    }
}

extern "C" void kernel_launch(void* const* d_in, const int* in_sizes, int n_in,
                              void* d_out, int out_size, void* d_ws, size_t ws_size,
                              hipStream_t stream) {
    const float* x     = (const float*)d_in[0];
    const float* cosA  = (const float*)d_in[1];
    const float* sinA  = (const float*)d_in[2];
    const float* bias  = (const float*)d_in[3];
    const float* gamma = (const float*)d_in[4];
    const float* beta  = (const float*)d_in[5];
    float* out = (float*)d_out;

    __bf16* Bp = (__bf16*)d_ws;   // 1 MB: fragment-packed bf16 amplitudes

    fkan_pack_b<<<dim3((NCHUNK * O_DIM * KC) / 8 / 256), dim3(256), 0, stream>>>(cosA, sinA, Bp);
    fkan_main<<<dim3(N_TOK / BN), dim3(512), 0, stream>>>(x, Bp, bias, gamma, beta, out);
}

// Round 6
// 98.232 us; speedup vs baseline: 1.0717x; 1.0717x over previous
//
#include <hip/hip_runtime.h>
#include <hip/hip_bf16.h>
#include <math.h>

// Problem constants
#define N_TOK 16384
#define I_DIM 128
#define O_DIM 128
#define G_DIM 16
// GEMM tiling
#define BN 32                       // n-rows per block
#define CI 4                        // i-values per K-chunk
#define KC (CI * G_DIM * 2)         // 128 k per chunk
#define NCHUNK (I_DIM / CI)         // 32 chunks
#define A_STRIDE 136                // bf16 elems per LDS A row (272 B)
#define ABUF (BN * A_STRIDE)        // 4352 elems = 8704 B per A buffer
#define C_STRIDE 132                // floats per LDS C row (epilogue)

typedef __bf16 bf16x8 __attribute__((ext_vector_type(8)));
typedef float  f32x4  __attribute__((ext_vector_type(4)));

// ---------------------------------------------------------------------------
// Pack cos/sin amplitudes (O,I,G) fp32 -> bf16 Bp in MFMA-FRAGMENT order:
//   element (frag*64 + lane)*8 + j, frag = ((c*4 + cg)*4 + ks)*2 + ot,
//   lane = quad*16 + row16, o = cg*32+ot*16+row16, i = c*4+ks,
//   g = quad*4 + (j>>1), s = j&1 (0=cos, 1=sin).
// Thread mapping = OUTPUT identity (tid = frag*64+lane): writes are fully
// contiguous (1 KB per wave-instr); reads are 64 B full-line gathers.
// ---------------------------------------------------------------------------
__global__ __launch_bounds__(256) void fkan_pack_b(
    const float* __restrict__ cosA, const float* __restrict__ sinA,
    __bf16* __restrict__ Bp)
{
    int tid   = blockIdx.x * 256 + threadIdx.x;   // 0 .. 65535
    int lane  = tid & 63;
    int frag  = tid >> 6;                         // 0 .. 1023
    int row16 = lane & 15, quad = lane >> 4;
    int ot = frag & 1, ks = (frag >> 1) & 3, cg = (frag >> 3) & 3, c = frag >> 5;
    int o  = cg * 32 + ot * 16 + row16;
    int i  = c * CI + ks;
    size_t sbase = ((size_t)o * I_DIM + i) * G_DIM + quad * 4;
    float4 cv = *(const float4*)(cosA + sbase);
    float4 sv = *(const float4*)(sinA + sbase);
    bf16x8 v;
    v[0] = (__bf16)cv.x; v[1] = (__bf16)sv.x;
    v[2] = (__bf16)cv.y; v[3] = (__bf16)sv.y;
    v[4] = (__bf16)cv.z; v[5] = (__bf16)sv.z;
    v[6] = (__bf16)cv.w; v[7] = (__bf16)sv.w;
    *(bf16x8*)(Bp + (size_t)tid * 8) = v;
}

// ---------------------------------------------------------------------------
// Fused: features (cos/sin of x*freq) -> bf16 MFMA GEMM -> bias -> LayerNorm
// Grid: 512 blocks x 256 threads (4 waves) = 2 INDEPENDENT blocks per CU:
// different blocks have different barriers, so one block's MFMA covers the
// other's ds-latency/barrier stalls (r4 showed sibling waves cannot).
// Block tile 32n x 128o; wave tile 32n x 32o (wave = cg; 2x2 of 16x16x32).
// B: fragment-packed coalesced global loads, register double-buffered.
// A: features double-buffered in LDS, split-harmonic staging (shalf).
// x: register relay prefetched 2 chunks ahead (r4-proven; r5's x-LDS reverted).
// ONE raw barrier per chunk, lgkm-only drain (B loads span barriers).
// ---------------------------------------------------------------------------
__global__ __launch_bounds__(256, 2) void fkan_main(
    const float* __restrict__ x,
    const __bf16* __restrict__ Bp,
    const float* __restrict__ bias,
    const float* __restrict__ gamma,
    const float* __restrict__ beta,
    float* __restrict__ out)
{
    // LDS: 2 x A buffer (32 x 136 bf16 = 8704 B each) = 17408 B -> 2 blocks/CU.
    // Epilogue C tile (32 x 132 f32 = 16896 B) reuses the same region.
    __shared__ __align__(16) __bf16 smem[2 * ABUF];
    __bf16* A0 = smem;
    __bf16* A1 = smem + ABUF;

    const int t     = threadIdx.x;
    const int lane  = t & 63;
    const int cg    = t >> 6;          // wave = o-column group (0..3)
    const int row16 = lane & 15;
    const int quad  = lane >> 4;
    const int n0    = blockIdx.x * BN;

    // feature-staging role: (row, i-within-chunk, g-half). shalf wave-uniform.
    const int srow  = (t & 127) >> 2;  // 0..31
    const int sil   = t & 3;           // 0..3
    const int shalf = t >> 7;          // 0: g=1..8, 1: g=9..16

    f32x4 acc[2][2];
#pragma unroll
    for (int mt = 0; mt < 2; ++mt)
#pragma unroll
        for (int ot = 0; ot < 2; ++ot)
            acc[mt][ot] = (f32x4){0.f, 0.f, 0.f, 0.f};

    bf16x8 bA[2][4], bB[2][4];         // [ot][ks] register double-buffer for B

    auto ld_x = [&](int c) -> float {
        return x[(size_t)(n0 + srow) * I_DIM + c * CI + sil];
    };

    // ---- fragment-packed coalesced B load: 8 x dwordx4 per wave per chunk ----
    auto ld_b = [&](int c, bf16x8 (&b)[2][4]) {
        const bf16x8* base = (const bf16x8*)Bp + ((size_t)(c * 4 + cg) * 8) * 64 + lane;
#pragma unroll
        for (int ks = 0; ks < 4; ++ks)
#pragma unroll
            for (int ot = 0; ot < 2; ++ot)
                b[ot][ks] = base[(ks * 2 + ot) * 64];
    };

    // ---- compute 16 bf16 features (one g-half) for (srow, .) -> LDS ----
    auto stage_a = [&](float xv, __bf16* Ab) {
        float s1, c1;
        __sincosf(xv, &s1, &c1);
        float cb = c1, sb = s1;        // base = (cos x, sin x)  [g=1]
        if (shalf) {                   // base = (cos 9x, sin 9x): 3 doublings + 1 step
            float cd = c1, sd = s1;
#pragma unroll
            for (int d = 0; d < 3; ++d) {
                float cn = cd * cd - sd * sd;
                float sn = 2.f * cd * sd;
                cd = cn; sd = sn;
            }
            cb = cd * c1 - sd * s1;
            sb = sd * c1 + cd * s1;
        }
        __align__(16) __bf16 feat[16];
        float cc_ = cb, ss_ = sb;
#pragma unroll
        for (int j = 0; j < 8; ++j) {  // 8 harmonics from base, step by x
            feat[2 * j]     = (__bf16)cc_;
            feat[2 * j + 1] = (__bf16)ss_;
            float cn = cc_ * c1 - ss_ * s1;
            float sn = ss_ * c1 + cc_ * s1;
            cc_ = cn; ss_ = sn;
        }
        bf16x8* dst = (bf16x8*)(Ab + srow * A_STRIDE + sil * 32 + shalf * 16);
        dst[0] = ((const bf16x8*)feat)[0];
        dst[1] = ((const bf16x8*)feat)[1];
    };

    // ---- one K-chunk phase: prefetch c+1 (B regs, A LDS, x scalar), MFMA c ----
    auto phase = [&](int c, const __bf16* Ar, __bf16* Aw,
                     bf16x8 (&bcur)[2][4], bf16x8 (&bnext)[2][4], float xs, float& xn) {
        const bool pf = (c + 1 < NCHUNK);
        if (pf) ld_b(c + 1, bnext);          // coalesced global loads, in flight
        if (c + 2 < NCHUNK) xn = ld_x(c + 2);
        if (pf) stage_a(xs, Aw);             // VALU chain + 2 ds_write (other buffer)

        __builtin_amdgcn_s_setprio(1);
#pragma unroll
        for (int ks = 0; ks < 4; ++ks) {
            bf16x8 a0 = *(const bf16x8*)(Ar + (row16)      * A_STRIDE + ks * 32 + quad * 8);
            bf16x8 a1 = *(const bf16x8*)(Ar + (16 + row16) * A_STRIDE + ks * 32 + quad * 8);
            acc[0][0] = __builtin_amdgcn_mfma_f32_16x16x32_bf16(a0, bcur[0][ks], acc[0][0], 0, 0, 0);
            acc[0][1] = __builtin_amdgcn_mfma_f32_16x16x32_bf16(a0, bcur[1][ks], acc[0][1], 0, 0, 0);
            acc[1][0] = __builtin_amdgcn_mfma_f32_16x16x32_bf16(a1, bcur[0][ks], acc[1][0], 0, 0, 0);
            acc[1][1] = __builtin_amdgcn_mfma_f32_16x16x32_bf16(a1, bcur[1][ks], acc[1][1], 0, 0, 0);
        }
        __builtin_amdgcn_s_setprio(0);

        asm volatile("s_waitcnt lgkmcnt(0)" ::: "memory");  // A writes visible, reads retired
        __builtin_amdgcn_sched_barrier(0);
        __builtin_amdgcn_s_barrier();        // vmcnt NOT drained: B prefetch spans barrier
    };

    // ---- prologue: stage chunk 0 (the only exposed latency) ----
    float xA = ld_x(0);
    float xB;
    ld_b(0, bA);
    stage_a(xA, A0);
    xB = ld_x(1);
    asm volatile("s_waitcnt lgkmcnt(0)" ::: "memory");
    __builtin_amdgcn_s_barrier();

    for (int cc = 0; cc < NCHUNK / 2; ++cc) {
        phase(2 * cc,     A0, A1, bA, bB, xB, xA);   // stages chunk 2cc+1 (x = xB)
        phase(2 * cc + 1, A1, A0, bB, bA, xA, xB);   // stages chunk 2cc+2 (x = xA)
    }

    // ---- epilogue: acc -> LDS C, bias + LayerNorm over O=128, store fp32 ----
    // C/D layout: col(o within 16) = lane&15, row(m within 16) = quad*4 + reg
    float* Cs = (float*)smem;          // safe: last barrier retired all A-buffer ops
#pragma unroll
    for (int mt = 0; mt < 2; ++mt)
#pragma unroll
        for (int ot = 0; ot < 2; ++ot)
#pragma unroll
            for (int r = 0; r < 4; ++r)
                Cs[(mt * 16 + quad * 4 + r) * C_STRIDE
                   + cg * 32 + ot * 16 + row16] = acc[mt][ot][r];
    __syncthreads();

    {
        const int r  = t >> 3;         // row within block (0..31)
        const int oc = t & 7;          // eighth of the O dim (16 cols each)
        const float* crow = Cs + r * C_STRIDE + oc * 16;
        float vals[16];
        float sum = 0.f, sumsq = 0.f;
#pragma unroll
        for (int j4 = 0; j4 < 4; ++j4) {
            f32x4 v4 = *(const f32x4*)(crow + 4 * j4);
#pragma unroll
            for (int e = 0; e < 4; ++e) {
                float v = v4[e] + bias[oc * 16 + 4 * j4 + e];
                vals[4 * j4 + e] = v;
                sum += v;
                sumsq += v * v;
            }
        }
        // combine the 8 threads of this row (adjacent lanes, bits 0-2)
        sum   += __shfl_xor(sum, 1);   sum   += __shfl_xor(sum, 2);   sum   += __shfl_xor(sum, 4);
        sumsq += __shfl_xor(sumsq, 1); sumsq += __shfl_xor(sumsq, 2); sumsq += __shfl_xor(sumsq, 4);
        float mu   = sum * (1.0f / O_DIM);
        float var  = sumsq * (1.0f / O_DIM) - mu * mu;
        float rstd = rsqrtf(var + 1e-5f);

        float* orow = out + (size_t)(n0 + r) * O_DIM + oc * 16;
#pragma unroll
        for (int j4 = 0; j4 < 4; ++j4) {
            float4 o4;
            o4.x = (vals[4*j4+0] - mu) * rstd * gamma[oc*16 + 4*j4+0] + beta[oc*16 + 4*j4+0];
            o4.y = (vals[4*j4+1] - mu) * rstd * gamma[oc*16 + 4*j4+1] + beta[oc*16 + 4*j4+1];
            o4.z = (vals[4*j4+2] - mu) * rstd * gamma[oc*16 + 4*j4+2] + beta[oc*16 + 4*j4+2];
            o4.w = (vals[4*j4+3] - mu) * rstd * gamma[oc*16 + 4*j4+3] + beta[oc*16 + 4*j4+3];
            *(float4*)(orow + 4 * j4) = o4;
        }
    }
}

extern "C" void kernel_launch(void* const* d_in, const int* in_sizes, int n_in,
                              void* d_out, int out_size, void* d_ws, size_t ws_size,
                              hipStream_t stream) {
    const float* x     = (const float*)d_in[0];
    const float* cosA  = (const float*)d_in[1];
    const float* sinA  = (const float*)d_in[2];
    const float* bias  = (const float*)d_in[3];
    const float* gamma = (const float*)d_in[4];
    const float* beta  = (const float*)d_in[5];
    float* out = (float*)d_out;

    __bf16* Bp = (__bf16*)d_ws;   // 1 MB: fragment-packed bf16 amplitudes

    fkan_pack_b<<<dim3(256), dim3(256), 0, stream>>>(cosA, sinA, Bp);
    fkan_main<<<dim3(N_TOK / BN), dim3(256), 0, stream>>>(x, Bp, bias, gamma, beta, out);
}